// Round 11
// baseline (904.915 us; speedup 1.0000x reference)
//
#include <hip/hip_runtime.h>
#include <hip/hip_bf16.h>

#define S_ 1024
#define D_ 128
#define V_ 100000
#define VSTRIPS_ 3136   // 32-row v-strips; 3125 valid (=100000), 11 zero pads
#define NPHASE_ 64      // 64 phases x 49 strips = 3136
#define N_ 4096
#define PADROWS_ 352.0f

typedef __attribute__((ext_vector_type(4))) float f32x4;
typedef __attribute__((ext_vector_type(8))) short bf16x8;

#define LOG2E_ 1.4426950408889634f
#define LN2_   0.6931471805599453f

__device__ __forceinline__ float exp2_fast(float x) {
#if __has_builtin(__builtin_amdgcn_exp2f)
    return __builtin_amdgcn_exp2f(x);
#else
    return exp2f(x);
#endif
}

// ---- kernel 1: normalize K -> bf16 in FRAGMENT-MAJOR layout ----
// Strip s (32 rows) occupies 8KB: frag f=nn*4+kk (1KB each), lane l holds
// row nn*16+(l&15), k-bytes kk*64+(l>>4)*16. ce_main loads B operands with
// perfectly coalesced dwordx4 (no LDS anywhere downstream).
__global__ void knorm_kernel(const float* __restrict__ K, char* __restrict__ Kn) {
    __shared__ char sm[8192];
    const int strip = blockIdx.x;
    const int tid = threadIdx.x;
    const int lane = tid & 63;
    const int wvv = tid >> 6;
    char* dst = Kn + (size_t)strip * 8192;
    if (strip >= 3125) {                       // zero pad strip
        const f32x4 z = {0.f, 0.f, 0.f, 0.f};
        *(f32x4*)(dst + tid * 32) = z;
        *(f32x4*)(dst + tid * 32 + 16) = z;
        return;
    }
    #pragma unroll
    for (int i = 0; i < 8; ++i) {
        int r = wvv * 8 + i;
        float2 v = ((const float2*)(K + ((size_t)strip * 32 + r) * D_))[lane];
        float ss = v.x * v.x + v.y * v.y;
        #pragma unroll
        for (int off = 32; off; off >>= 1) ss += __shfl_xor(ss, off);
        float rn = rsqrtf(ss);
        __hip_bfloat162 o;
        o.x = __float2bfloat16(v.x * rn);
        o.y = __float2bfloat16(v.y * rn);
        int addr = (r >> 4) * 4096 + (lane >> 4) * 1024 + ((lane >> 2) & 3) * 256
                 + (r & 15) * 16 + (lane & 3) * 4;
        *(__hip_bfloat162*)(sm + addr) = o;
    }
    __syncthreads();
    *(f32x4*)(dst + tid * 32)      = *(const f32x4*)(sm + tid * 32);
    *(f32x4*)(dst + tid * 32 + 16) = *(const f32x4*)(sm + tid * 32 + 16);
}

// ---- kernel 2: gather + normalize Q -> bf16 row-major (pre-scaled log2 e); zero Ssum ----
__global__ void qnorm_kernel(const float* __restrict__ Q, const int* __restrict__ loc,
                             __hip_bfloat16* __restrict__ Qn, float* __restrict__ Ssum) {
    int w = (blockIdx.x * blockDim.x + threadIdx.x) >> 6;
    int lane = threadIdx.x & 63;
    if (w >= N_) return;
    if (lane == 0) Ssum[w] = 0.f;
    int b = loc[2 * w], s = loc[2 * w + 1];
    float2 v = ((const float2*)(Q + ((size_t)b * S_ + (size_t)s) * D_))[lane];
    float ss = v.x * v.x + v.y * v.y;
    #pragma unroll
    for (int off = 32; off; off >>= 1) ss += __shfl_xor(ss, off);
    float rn = rsqrtf(ss) * LOG2E_;        // exp2 domain
    __hip_bfloat162 o;
    o.x = __float2bfloat16(v.x * rn);
    o.y = __float2bfloat16(v.y * rn);
    ((__hip_bfloat162*)(Qn + (size_t)w * D_))[lane] = o;
}

// ---- kernel 3: main  sum_v exp2(q . k_v)  -- NO LDS, NO BARRIERS ----
// Kn fragment-major: per strip, 8 coalesced dwordx4 = the wave's whole B set.
// Block 256q x 32v (4 waves share the strip stream -> L1/L2 co-hit).
// Wave: 64q x 32v (m=4, nn=2). Register double-buffer, one strip ahead.
// grid (16, NPHASE_) = 1024 blocks = 4 blocks/CU = 4 waves/SIMD: enough
// independent anti-phase waves to pack the MFMA pipe (R10 had only 2).
__global__ __launch_bounds__(256, 4) void ce_main(
    const __hip_bfloat16* __restrict__ Qn,
    const char* __restrict__ Kn,
    float* __restrict__ Ssum)
{
    const int tid  = threadIdx.x;
    const int lane = tid & 63;
    const int wv   = tid >> 6;
    const int r0   = lane & 15;
    const int hi   = lane >> 4;          // 0..3

    // grid (16,64): XCD owns 8 whole phase-groups (all 16 q-blocks of each)
    const int fid   = blockIdx.y * 16 + blockIdx.x;
    const int xcd   = fid & 7;
    const int idx   = fid >> 3;              // 0..127
    const int phase = xcd * 8 + (idx >> 4);  // 0..63
    const int qb    = idx & 15;              // 0..15 (256 q-rows each)

    // ---- Q fragments -> registers (loop-invariant) ----
    bf16x8 afr[4][4];
    {
        const char* qsrc = (const char*)Qn + ((size_t)qb * 256 + wv * 64 + r0) * 256
                         + (hi << 4);
        #pragma unroll
        for (int m = 0; m < 4; ++m)
            #pragma unroll
            for (int kk = 0; kk < 4; ++kk)
                afr[m][kk] = *(const bf16x8*)(qsrc + m * 4096 + kk * 64);
    }

    // strip j (j=0..48) -> global strip phase + NPHASE_*j
    const char* kvbase = Kn + (size_t)phase * 8192 + (lane << 4);

#define LOADSET(R, j) do {                                                   \
        const char* p  = kvbase + (size_t)(j) * (8192 * NPHASE_);            \
        const char* p2 = p + 4096;                                           \
        R[0] = *(const bf16x8*)(p);         R[1] = *(const bf16x8*)(p + 1024); \
        R[2] = *(const bf16x8*)(p + 2048);  R[3] = *(const bf16x8*)(p + 3072); \
        R[4] = *(const bf16x8*)(p2);        R[5] = *(const bf16x8*)(p2 + 1024);\
        R[6] = *(const bf16x8*)(p2 + 2048); R[7] = *(const bf16x8*)(p2 + 3072);\
    } while (0)

#define COMPUTE(R, ACC) do {                                                 \
        __builtin_amdgcn_s_setprio(1);                                       \
        _Pragma("unroll")                                                    \
        for (int m = 0; m < 4; ++m) {                                        \
            ACC[m][0] = __builtin_amdgcn_mfma_f32_16x16x32_bf16(afr[m][0], R[0], fz, 0, 0, 0); \
            ACC[m][1] = __builtin_amdgcn_mfma_f32_16x16x32_bf16(afr[m][0], R[4], fz, 0, 0, 0); \
        }                                                                    \
        _Pragma("unroll")                                                    \
        for (int kk = 1; kk < 4; ++kk) {                                     \
            _Pragma("unroll")                                                \
            for (int m = 0; m < 4; ++m) {                                    \
                ACC[m][0] = __builtin_amdgcn_mfma_f32_16x16x32_bf16(afr[m][kk], R[kk],     ACC[m][0], 0, 0, 0); \
                ACC[m][1] = __builtin_amdgcn_mfma_f32_16x16x32_bf16(afr[m][kk], R[4 + kk], ACC[m][1], 0, 0, 0); \
            }                                                                \
        }                                                                    \
        __builtin_amdgcn_s_setprio(0);                                       \
    } while (0)

#define EXP2S(ACC) do {                                                      \
        _Pragma("unroll")                                                    \
        for (int m = 0; m < 4; ++m)                                          \
            _Pragma("unroll")                                                \
            for (int q = 0; q < 4; ++q)                                      \
                psum[m][q] += exp2_fast(ACC[m][0][q]) + exp2_fast(ACC[m][1][q]); \
    } while (0)

    float psum[4][4];
    #pragma unroll
    for (int m = 0; m < 4; ++m)
        #pragma unroll
        for (int q = 0; q < 4; ++q) psum[m][q] = 0.f;

    const f32x4 fz = {0.f, 0.f, 0.f, 0.f};
    f32x4 accE[4][2], accO[4][2];
    #pragma unroll
    for (int m = 0; m < 4; ++m)
        #pragma unroll
        for (int nn = 0; nn < 2; ++nn)
            accO[m][nn] = (f32x4){-16384.f, -16384.f, -16384.f, -16384.f}; // exp2 -> 0

    bf16x8 RA[8], RB[8];
    LOADSET(RA, 0);
    #pragma unroll 1
    for (int j = 0; j < 48; j += 2) {
        LOADSET(RB, j + 1);          // prefetch next strip
        EXP2S(accO);                 // strip j-1 exp2 under load latency
        COMPUTE(RA, accE);           // strip j
        LOADSET(RA, j + 2);          // j+2 <= 48: valid
        EXP2S(accE);                 // strip j
        COMPUTE(RB, accO);           // strip j+1
    }
    // epilogue: strip 48 (already in RA)
    EXP2S(accO);                     // strip 47
    COMPUTE(RA, accE);               // strip 48
    EXP2S(accE);                     // strip 48

#undef LOADSET
#undef COMPUTE
#undef EXP2S

    // reduce over 16 lanes (same q-rows, different v-cols), then atomics
    #pragma unroll
    for (int m = 0; m < 4; ++m) {
        #pragma unroll
        for (int q = 0; q < 4; ++q) {
            float v = psum[m][q];
            v += __shfl_xor(v, 1);
            v += __shfl_xor(v, 2);
            v += __shfl_xor(v, 4);
            v += __shfl_xor(v, 8);
            if (r0 == 0) {
                int row = qb * 256 + wv * 64 + m * 16 + hi * 4 + q;
                atomicAdd(&Ssum[row], v);
            }
        }
    }
}

// ---- kernel 4: per-row term = log(S - PADROWS) - true_logit ----
// Kn fragment-major: row lab, byte b=4*lane at
// (lab>>5)*8192 + ((lab>>4)&1)*4096 + (lane>>4)*1024 + ((lane>>2)&3)*256 + (lab&15)*16 + (lane&3)*4
__global__ void term_kernel(const __hip_bfloat16* __restrict__ Qn,
                            const char* __restrict__ Kn,
                            const int* __restrict__ labels,
                            const float* __restrict__ Ssum,
                            float* __restrict__ T) {
    int w = (blockIdx.x * blockDim.x + threadIdx.x) >> 6;
    int lane = threadIdx.x & 63;
    if (w >= N_) return;
    int lab = labels[w];
    __hip_bfloat162 q2 = ((const __hip_bfloat162*)(Qn + (size_t)w * D_))[lane];
    const char* kaddr = Kn + ((size_t)(lab >> 5)) * 8192 + ((lab >> 4) & 1) * 4096
                      + (lane >> 4) * 1024 + ((lane >> 2) & 3) * 256
                      + (lab & 15) * 16 + (lane & 3) * 4;
    __hip_bfloat162 k2 = *(const __hip_bfloat162*)kaddr;
    float d = __bfloat162float(q2.x) * __bfloat162float(k2.x)
            + __bfloat162float(q2.y) * __bfloat162float(k2.y);
    #pragma unroll
    for (int off = 32; off; off >>= 1) d += __shfl_xor(d, off);
    if (lane == 0) T[w] = logf(Ssum[w] - PADROWS_) - d * LN2_;
}

// ---- kernel 5: mean over N ----
__global__ void reduce_kernel(const float* __restrict__ T, float* __restrict__ out) {
    __shared__ float sm[4];
    float s = 0.f;
    for (int i = threadIdx.x; i < N_; i += 256) s += T[i];
    #pragma unroll
    for (int off = 32; off; off >>= 1) s += __shfl_xor(s, off);
    if ((threadIdx.x & 63) == 0) sm[threadIdx.x >> 6] = s;
    __syncthreads();
    if (threadIdx.x == 0) out[0] = (sm[0] + sm[1] + sm[2] + sm[3]) * (1.0f / (float)N_);
}

extern "C" void kernel_launch(void* const* d_in, const int* in_sizes, int n_in,
                              void* d_out, int out_size, void* d_ws, size_t ws_size,
                              hipStream_t stream) {
    (void)in_sizes; (void)n_in; (void)out_size; (void)ws_size;
    const float* Q   = (const float*)d_in[0];
    const float* K   = (const float*)d_in[1];
    const int* loc   = (const int*)d_in[2];
    const int* labels= (const int*)d_in[3];
    float* out = (float*)d_out;

    char* ws = (char*)d_ws;
    char* Kn           = ws;                                        // 3136*8192 = 25,690,112 B
    __hip_bfloat16* Qn = (__hip_bfloat16*)(ws + 25690112);          // N_*128*2  =  1,048,576 B
    float* Ssum        = (float*)(ws + 25690112 + 1048576);         // N_*4
    float* T           = Ssum + N_;                                  // N_*4

    knorm_kernel<<<VSTRIPS_, 256, 0, stream>>>(K, Kn);
    qnorm_kernel<<<N_ / 4, 256, 0, stream>>>(Q, loc, Qn, Ssum);
    ce_main<<<dim3(16, NPHASE_), 256, 0, stream>>>(Qn, Kn, Ssum);
    term_kernel<<<N_ / 4, 256, 0, stream>>>(Qn, Kn, labels, Ssum, T);
    reduce_kernel<<<1, 256, 0, stream>>>(T, out);
}

// Round 12
// 136.459 us; speedup vs baseline: 6.6314x; 6.6314x over previous
//
#include <hip/hip_runtime.h>
#include <hip/hip_bf16.h>

#define S_ 1024
#define D_ 128
#define V_ 100000
#define VSTRIPS_ 3136   // 32-row v-strips; 3125 valid, 11 zero pads
#define NPHASE_ 32      // 32 phases x 98 strips = 3136
#define N_ 4096
#define PADROWS_ 352.0f

typedef __attribute__((ext_vector_type(4))) float f32x4;
typedef __attribute__((ext_vector_type(16))) float f32x16;
typedef __attribute__((ext_vector_type(8))) short bf16x8;

#define LOG2E_ 1.4426950408889634f
#define LN2_   0.6931471805599453f

__device__ __forceinline__ float exp2_fast(float x) {
#if __has_builtin(__builtin_amdgcn_exp2f)
    return __builtin_amdgcn_exp2f(x);
#else
    return exp2f(x);
#endif
}

// ---- kernel 1: normalize K -> bf16, FRAGMENT-MAJOR for mfma 32x32x16 ----
// Strip s (32 v-rows = B cols) = 8KB: frag kb (0..7, 1KB each) holds K-block
// kb*16..+16. Lane l: col=l&31 -> v-row, k = kb*16 + 8*(l>>5) + [0..7].
// Element (r, k): kb=k>>4, lane'=r+32*((k>>3)&1), j=k&7
//   addr = (k>>4)*1024 + (r + 32*((k>>3)&1))*16 + (k&7)*2
__global__ void knorm_kernel(const float* __restrict__ K, char* __restrict__ Kn) {
    __shared__ char sm[8192];
    const int strip = blockIdx.x;
    const int tid = threadIdx.x;
    const int lane = tid & 63;
    const int wvv = tid >> 6;
    char* dst = Kn + (size_t)strip * 8192;
    if (strip >= 3125) {                       // zero pad strip
        const f32x4 z = {0.f, 0.f, 0.f, 0.f};
        *(f32x4*)(dst + tid * 32) = z;
        *(f32x4*)(dst + tid * 32 + 16) = z;
        return;
    }
    #pragma unroll
    for (int i = 0; i < 8; ++i) {
        int r = wvv * 8 + i;
        float2 v = ((const float2*)(K + ((size_t)strip * 32 + r) * D_))[lane];
        float ss = v.x * v.x + v.y * v.y;
        #pragma unroll
        for (int off = 32; off; off >>= 1) ss += __shfl_xor(ss, off);
        float rn = rsqrtf(ss);
        __hip_bfloat162 o;
        o.x = __float2bfloat16(v.x * rn);
        o.y = __float2bfloat16(v.y * rn);
        // k1 = 2*lane: kb=lane>>3, half=(lane>>2)&1, j=2*(lane&3)
        int addr = ((lane >> 3) << 10) + ((r + ((lane >> 2) & 1) * 32) << 4)
                 + ((lane & 3) << 2);
        *(__hip_bfloat162*)(sm + addr) = o;
    }
    __syncthreads();
    *(f32x4*)(dst + tid * 32)      = *(const f32x4*)(sm + tid * 32);
    *(f32x4*)(dst + tid * 32 + 16) = *(const f32x4*)(sm + tid * 32 + 16);
}

// ---- kernel 2: gather + normalize Q -> bf16 row-major (pre-scaled log2 e); zero Ssum ----
__global__ void qnorm_kernel(const float* __restrict__ Q, const int* __restrict__ loc,
                             __hip_bfloat16* __restrict__ Qn, float* __restrict__ Ssum) {
    int w = (blockIdx.x * blockDim.x + threadIdx.x) >> 6;
    int lane = threadIdx.x & 63;
    if (w >= N_) return;
    if (lane == 0) Ssum[w] = 0.f;
    int b = loc[2 * w], s = loc[2 * w + 1];
    float2 v = ((const float2*)(Q + ((size_t)b * S_ + (size_t)s) * D_))[lane];
    float ss = v.x * v.x + v.y * v.y;
    #pragma unroll
    for (int off = 32; off; off >>= 1) ss += __shfl_xor(ss, off);
    float rn = rsqrtf(ss) * LOG2E_;        // exp2 domain
    __hip_bfloat162 o;
    o.x = __float2bfloat16(v.x * rn);
    o.y = __float2bfloat16(v.y * rn);
    ((__hip_bfloat162*)(Qn + (size_t)w * D_))[lane] = o;
}

// ---- kernel 3: main  sum_v exp2(q . k_v)  -- NO LDS, NO BARRIERS, 32x32x16 ----
// Wave: 64q x 32v = 2 q-blocks of 32x32; 8 k-blocks; 16 MFMA/strip (was 32).
// B frags: 8 coalesced dwordx4/strip. A (Q) in regs: row=lane&31,
// k = kb*16 + 8*(lane>>5) + [0..7]. Register double-buffer one strip ahead;
// exp2 of previous strip's acc bank between load-issue and MFMA cluster.
__global__ __launch_bounds__(256, 2) void ce_main(
    const __hip_bfloat16* __restrict__ Qn,
    const char* __restrict__ Kn,
    float* __restrict__ Ssum)
{
    const int tid  = threadIdx.x;
    const int lane = tid & 63;
    const int wv   = tid >> 6;
    const int hi2  = lane >> 5;          // 0..1

    // grid (16,32): XCD owns 4 whole phase-groups (all 16 q-blocks of each)
    const int fid   = blockIdx.y * 16 + blockIdx.x;
    const int xcd   = fid & 7;
    const int idx   = fid >> 3;          // 0..63
    const int phase = xcd * 4 + (idx >> 4);   // 0..31
    const int qb    = idx & 15;          // 0..15 (256 q-rows each)

    // ---- Q fragments -> registers (loop-invariant) ----
    // afr[qblk][kb]: q-row = qb*256 + wv*64 + qblk*32 + (lane&31)
    bf16x8 afr[2][8];
    {
        const char* qsrc = (const char*)Qn
                         + ((size_t)qb * 256 + wv * 64 + (lane & 31)) * 256
                         + (hi2 << 4);
        #pragma unroll
        for (int qk = 0; qk < 2; ++qk)
            #pragma unroll
            for (int kb = 0; kb < 8; ++kb)
                afr[qk][kb] = *(const bf16x8*)(qsrc + qk * 8192 + kb * 32);
    }

    // strip j (0..97) at phase + NPHASE_*j; frag kb at +kb*1024 + lane*16
    const char* kvbase = Kn + (size_t)phase * 8192 + (lane << 4);

#define LOADSET(R, j) do {                                                   \
        const char* p = kvbase + (size_t)(j) * (8192 * NPHASE_);             \
        R[0] = *(const bf16x8*)(p);         R[1] = *(const bf16x8*)(p + 1024); \
        R[2] = *(const bf16x8*)(p + 2048);  R[3] = *(const bf16x8*)(p + 3072); \
        R[4] = *(const bf16x8*)(p + 4096);  R[5] = *(const bf16x8*)(p + 5120); \
        R[6] = *(const bf16x8*)(p + 6144);  R[7] = *(const bf16x8*)(p + 7168); \
    } while (0)

#define COMPUTE(R, ACC) do {                                                 \
        __builtin_amdgcn_s_setprio(1);                                       \
        ACC[0] = __builtin_amdgcn_mfma_f32_32x32x16_bf16(afr[0][0], R[0], fz16, 0, 0, 0); \
        ACC[1] = __builtin_amdgcn_mfma_f32_32x32x16_bf16(afr[1][0], R[0], fz16, 0, 0, 0); \
        _Pragma("unroll")                                                    \
        for (int kb = 1; kb < 8; ++kb) {                                     \
            ACC[0] = __builtin_amdgcn_mfma_f32_32x32x16_bf16(afr[0][kb], R[kb], ACC[0], 0, 0, 0); \
            ACC[1] = __builtin_amdgcn_mfma_f32_32x32x16_bf16(afr[1][kb], R[kb], ACC[1], 0, 0, 0); \
        }                                                                    \
        __builtin_amdgcn_s_setprio(0);                                       \
    } while (0)

#define EXP2S(ACC) do {                                                      \
        _Pragma("unroll")                                                    \
        for (int qk = 0; qk < 2; ++qk)                                       \
            _Pragma("unroll")                                                \
            for (int r = 0; r < 16; ++r)                                     \
                psum[qk][r] += exp2_fast(ACC[qk][r]);                        \
    } while (0)

    float psum[2][16];
    #pragma unroll
    for (int qk = 0; qk < 2; ++qk)
        #pragma unroll
        for (int r = 0; r < 16; ++r) psum[qk][r] = 0.f;

    const f32x16 fz16 = {0.f,0.f,0.f,0.f,0.f,0.f,0.f,0.f,
                         0.f,0.f,0.f,0.f,0.f,0.f,0.f,0.f};
    f32x16 accE[2], accO[2];
    accO[0] = fz16 - 16384.f;   // exp2 -> 0 for the priming EXP2S
    accO[1] = accO[0];

    bf16x8 RA[8], RB[8];
    LOADSET(RA, 0);
    #pragma unroll 1
    for (int j = 0; j < 96; j += 2) {
        LOADSET(RB, j + 1);          // prefetch next strip
        EXP2S(accO);                 // strip j-1 exp2 under load latency
        COMPUTE(RA, accE);           // strip j
        LOADSET(RA, j + 2);
        EXP2S(accE);                 // strip j
        COMPUTE(RB, accO);           // strip j+1
    }
    // epilogue: strips 96 (RA already loaded), 97
    LOADSET(RB, 97);
    EXP2S(accO);                     // strip 95
    COMPUTE(RA, accE);               // strip 96
    EXP2S(accE);                     // strip 96
    COMPUTE(RB, accO);               // strip 97
    EXP2S(accO);                     // strip 97

#undef LOADSET
#undef COMPUTE
#undef EXP2S

    // psum[qk][reg]: row = qblk*32 + (reg&3)+8*(reg>>2)+4*hi2, col = lane&31.
    // Sum over cols: xor-reduce within each 32-lane half, then atomics.
    #pragma unroll
    for (int qk = 0; qk < 2; ++qk) {
        #pragma unroll
        for (int r = 0; r < 16; ++r) {
            float v = psum[qk][r];
            v += __shfl_xor(v, 1);
            v += __shfl_xor(v, 2);
            v += __shfl_xor(v, 4);
            v += __shfl_xor(v, 8);
            v += __shfl_xor(v, 16);
            if ((lane & 31) == 0) {
                int row = qb * 256 + wv * 64 + qk * 32
                        + (r & 3) + 8 * (r >> 2) + 4 * hi2;
                atomicAdd(&Ssum[row], v);
            }
        }
    }
}

// ---- kernel 4: per-row term = log(S - PADROWS) - true_logit ----
// Kn fragment-major (32x32x16 layout): label row lab, k1=2*lane:
// strip=lab>>5, addr = (lane>>3)*1024 + ((lab&31) + 32*((lane>>2)&1))*16 + (lane&3)*4
__global__ void term_kernel(const __hip_bfloat16* __restrict__ Qn,
                            const char* __restrict__ Kn,
                            const int* __restrict__ labels,
                            const float* __restrict__ Ssum,
                            float* __restrict__ T) {
    int w = (blockIdx.x * blockDim.x + threadIdx.x) >> 6;
    int lane = threadIdx.x & 63;
    if (w >= N_) return;
    int lab = labels[w];
    __hip_bfloat162 q2 = ((const __hip_bfloat162*)(Qn + (size_t)w * D_))[lane];
    const char* kaddr = Kn + ((size_t)(lab >> 5)) * 8192
                      + ((lane >> 3) << 10)
                      + (((lab & 31) + ((lane >> 2) & 1) * 32) << 4)
                      + ((lane & 3) << 2);
    __hip_bfloat162 k2 = *(const __hip_bfloat162*)kaddr;
    float d = __bfloat162float(q2.x) * __bfloat162float(k2.x)
            + __bfloat162float(q2.y) * __bfloat162float(k2.y);
    #pragma unroll
    for (int off = 32; off; off >>= 1) d += __shfl_xor(d, off);
    if (lane == 0) T[w] = logf(Ssum[w] - PADROWS_) - d * LN2_;
}

// ---- kernel 5: mean over N ----
__global__ void reduce_kernel(const float* __restrict__ T, float* __restrict__ out) {
    __shared__ float sm[4];
    float s = 0.f;
    for (int i = threadIdx.x; i < N_; i += 256) s += T[i];
    #pragma unroll
    for (int off = 32; off; off >>= 1) s += __shfl_xor(s, off);
    if ((threadIdx.x & 63) == 0) sm[threadIdx.x >> 6] = s;
    __syncthreads();
    if (threadIdx.x == 0) out[0] = (sm[0] + sm[1] + sm[2] + sm[3]) * (1.0f / (float)N_);
}

extern "C" void kernel_launch(void* const* d_in, const int* in_sizes, int n_in,
                              void* d_out, int out_size, void* d_ws, size_t ws_size,
                              hipStream_t stream) {
    (void)in_sizes; (void)n_in; (void)out_size; (void)ws_size;
    const float* Q   = (const float*)d_in[0];
    const float* K   = (const float*)d_in[1];
    const int* loc   = (const int*)d_in[2];
    const int* labels= (const int*)d_in[3];
    float* out = (float*)d_out;

    char* ws = (char*)d_ws;
    char* Kn           = ws;                                        // 3136*8192 = 25,690,112 B
    __hip_bfloat16* Qn = (__hip_bfloat16*)(ws + 25690112);          // N_*128*2  =  1,048,576 B
    float* Ssum        = (float*)(ws + 25690112 + 1048576);         // N_*4
    float* T           = Ssum + N_;                                  // N_*4

    knorm_kernel<<<VSTRIPS_, 256, 0, stream>>>(K, Kn);
    qnorm_kernel<<<N_ / 4, 256, 0, stream>>>(Q, loc, Qn, Ssum);
    ce_main<<<dim3(16, NPHASE_), 256, 0, stream>>>(Qn, Kn, Ssum);
    term_kernel<<<N_ / 4, 256, 0, stream>>>(Qn, Kn, labels, Ssum, T);
    reduce_kernel<<<1, 256, 0, stream>>>(T, out);
}

// Round 13
// 117.139 us; speedup vs baseline: 7.7252x; 1.1649x over previous
//
#include <hip/hip_runtime.h>
#include <hip/hip_bf16.h>

#define S_ 1024
#define D_ 128
#define V_ 100000
#define VSTRIPS_ 3136   // 32-row v-strips; 3125 valid (=100000), 11 zero pads
#define NPHASE_ 64      // 64 phases x 49 strips = 3136
#define N_ 4096
#define PADROWS_ 352.0f

typedef __attribute__((ext_vector_type(4))) float f32x4;
typedef __attribute__((ext_vector_type(8))) short bf16x8;

#define LOG2E_ 1.4426950408889634f
#define LN2_   0.6931471805599453f

__device__ __forceinline__ float exp2_fast(float x) {
#if __has_builtin(__builtin_amdgcn_exp2f)
    return __builtin_amdgcn_exp2f(x);
#else
    return exp2f(x);
#endif
}

// ---- kernel 1: normalize K -> bf16 in FRAGMENT-MAJOR layout (16x16x32) ----
// Strip s (32 rows) occupies 8KB: frag f=nn*4+kk (1KB each), lane l holds
// row nn*16+(l&15), k-bytes kk*64+(l>>4)*16. ce_main loads B operands with
// perfectly coalesced dwordx4 (no LDS anywhere downstream).
__global__ void knorm_kernel(const float* __restrict__ K, char* __restrict__ Kn) {
    __shared__ char sm[8192];
    const int strip = blockIdx.x;
    const int tid = threadIdx.x;
    const int lane = tid & 63;
    const int wvv = tid >> 6;
    char* dst = Kn + (size_t)strip * 8192;
    if (strip >= 3125) {                       // zero pad strip
        const f32x4 z = {0.f, 0.f, 0.f, 0.f};
        *(f32x4*)(dst + tid * 32) = z;
        *(f32x4*)(dst + tid * 32 + 16) = z;
        return;
    }
    #pragma unroll
    for (int i = 0; i < 8; ++i) {
        int r = wvv * 8 + i;
        float2 v = ((const float2*)(K + ((size_t)strip * 32 + r) * D_))[lane];
        float ss = v.x * v.x + v.y * v.y;
        #pragma unroll
        for (int off = 32; off; off >>= 1) ss += __shfl_xor(ss, off);
        float rn = rsqrtf(ss);
        __hip_bfloat162 o;
        o.x = __float2bfloat16(v.x * rn);
        o.y = __float2bfloat16(v.y * rn);
        int addr = (r >> 4) * 4096 + (lane >> 4) * 1024 + ((lane >> 2) & 3) * 256
                 + (r & 15) * 16 + (lane & 3) * 4;
        *(__hip_bfloat162*)(sm + addr) = o;
    }
    __syncthreads();
    *(f32x4*)(dst + tid * 32)      = *(const f32x4*)(sm + tid * 32);
    *(f32x4*)(dst + tid * 32 + 16) = *(const f32x4*)(sm + tid * 32 + 16);
}

// ---- kernel 2: gather + normalize Q -> bf16 row-major (pre-scaled log2 e); zero Ssum ----
__global__ void qnorm_kernel(const float* __restrict__ Q, const int* __restrict__ loc,
                             __hip_bfloat16* __restrict__ Qn, float* __restrict__ Ssum) {
    int w = (blockIdx.x * blockDim.x + threadIdx.x) >> 6;
    int lane = threadIdx.x & 63;
    if (w >= N_) return;
    if (lane == 0) Ssum[w] = 0.f;
    int b = loc[2 * w], s = loc[2 * w + 1];
    float2 v = ((const float2*)(Q + ((size_t)b * S_ + (size_t)s) * D_))[lane];
    float ss = v.x * v.x + v.y * v.y;
    #pragma unroll
    for (int off = 32; off; off >>= 1) ss += __shfl_xor(ss, off);
    float rn = rsqrtf(ss) * LOG2E_;        // exp2 domain
    __hip_bfloat162 o;
    o.x = __float2bfloat16(v.x * rn);
    o.y = __float2bfloat16(v.y * rn);
    ((__hip_bfloat162*)(Qn + (size_t)w * D_))[lane] = o;
}

// ---- kernel 3: main  sum_v exp2(q . k_v)  -- NO LDS, NO BARRIERS ----
// R10 body verbatim; only the grid changed: (16, 64) = 1024 blocks =
// 4 blocks/CU = 4 waves/SIMD (VGPR 112 <= 128 cap of (256,2) -> 4 fit).
// Kn fragment-major: per strip, 8 coalesced dwordx4 = the wave's whole B set.
// Wave: 64q x 32v (m=4, nn=2). Register double-buffer, one strip ahead.
__global__ __launch_bounds__(256, 2) void ce_main(
    const __hip_bfloat16* __restrict__ Qn,
    const char* __restrict__ Kn,
    float* __restrict__ Ssum)
{
    const int tid  = threadIdx.x;
    const int lane = tid & 63;
    const int wv   = tid >> 6;
    const int r0   = lane & 15;
    const int hi   = lane >> 4;          // 0..3

    // grid (16,64): XCD owns 8 whole phase-groups (all 16 q-blocks of each)
    const int fid   = blockIdx.y * 16 + blockIdx.x;
    const int xcd   = fid & 7;
    const int idx   = fid >> 3;              // 0..127
    const int phase = xcd * 8 + (idx >> 4);  // 0..63
    const int qb    = idx & 15;              // 0..15 (256 q-rows each)

    // ---- Q fragments -> registers (loop-invariant) ----
    bf16x8 afr[4][4];
    {
        const char* qsrc = (const char*)Qn + ((size_t)qb * 256 + wv * 64 + r0) * 256
                         + (hi << 4);
        #pragma unroll
        for (int m = 0; m < 4; ++m)
            #pragma unroll
            for (int kk = 0; kk < 4; ++kk)
                afr[m][kk] = *(const bf16x8*)(qsrc + m * 4096 + kk * 64);
    }

    // strip j (j=0..48) -> global strip phase + NPHASE_*j
    const char* kvbase = Kn + (size_t)phase * 8192 + (lane << 4);

#define LOADSET(R, j) do {                                                   \
        const char* p  = kvbase + (size_t)(j) * (8192 * NPHASE_);            \
        const char* p2 = p + 4096;                                           \
        R[0] = *(const bf16x8*)(p);         R[1] = *(const bf16x8*)(p + 1024); \
        R[2] = *(const bf16x8*)(p + 2048);  R[3] = *(const bf16x8*)(p + 3072); \
        R[4] = *(const bf16x8*)(p2);        R[5] = *(const bf16x8*)(p2 + 1024);\
        R[6] = *(const bf16x8*)(p2 + 2048); R[7] = *(const bf16x8*)(p2 + 3072);\
    } while (0)

#define COMPUTE(R, ACC) do {                                                 \
        __builtin_amdgcn_s_setprio(1);                                       \
        _Pragma("unroll")                                                    \
        for (int m = 0; m < 4; ++m) {                                        \
            ACC[m][0] = __builtin_amdgcn_mfma_f32_16x16x32_bf16(afr[m][0], R[0], fz, 0, 0, 0); \
            ACC[m][1] = __builtin_amdgcn_mfma_f32_16x16x32_bf16(afr[m][0], R[4], fz, 0, 0, 0); \
        }                                                                    \
        _Pragma("unroll")                                                    \
        for (int kk = 1; kk < 4; ++kk) {                                     \
            _Pragma("unroll")                                                \
            for (int m = 0; m < 4; ++m) {                                    \
                ACC[m][0] = __builtin_amdgcn_mfma_f32_16x16x32_bf16(afr[m][kk], R[kk],     ACC[m][0], 0, 0, 0); \
                ACC[m][1] = __builtin_amdgcn_mfma_f32_16x16x32_bf16(afr[m][kk], R[4 + kk], ACC[m][1], 0, 0, 0); \
            }                                                                \
        }                                                                    \
        __builtin_amdgcn_s_setprio(0);                                       \
    } while (0)

#define EXP2S(ACC) do {                                                      \
        _Pragma("unroll")                                                    \
        for (int m = 0; m < 4; ++m)                                          \
            _Pragma("unroll")                                                \
            for (int q = 0; q < 4; ++q)                                      \
                psum[m][q] += exp2_fast(ACC[m][0][q]) + exp2_fast(ACC[m][1][q]); \
    } while (0)

    float psum[4][4];
    #pragma unroll
    for (int m = 0; m < 4; ++m)
        #pragma unroll
        for (int q = 0; q < 4; ++q) psum[m][q] = 0.f;

    const f32x4 fz = {0.f, 0.f, 0.f, 0.f};
    f32x4 accE[4][2], accO[4][2];
    #pragma unroll
    for (int m = 0; m < 4; ++m)
        #pragma unroll
        for (int nn = 0; nn < 2; ++nn)
            accO[m][nn] = (f32x4){-16384.f, -16384.f, -16384.f, -16384.f}; // exp2 -> 0

    bf16x8 RA[8], RB[8];
    LOADSET(RA, 0);
    #pragma unroll 1
    for (int j = 0; j < 48; j += 2) {
        LOADSET(RB, j + 1);          // prefetch next strip
        EXP2S(accO);                 // strip j-1 exp2 under load latency
        COMPUTE(RA, accE);           // strip j
        LOADSET(RA, j + 2);          // j+2 <= 48: valid
        EXP2S(accE);                 // strip j
        COMPUTE(RB, accO);           // strip j+1
    }
    // epilogue: strip 48 (already in RA)
    EXP2S(accO);                     // strip 47
    COMPUTE(RA, accE);               // strip 48
    EXP2S(accE);                     // strip 48

#undef LOADSET
#undef COMPUTE
#undef EXP2S

    // reduce over 16 lanes (same q-rows, different v-cols), then atomics
    #pragma unroll
    for (int m = 0; m < 4; ++m) {
        #pragma unroll
        for (int q = 0; q < 4; ++q) {
            float v = psum[m][q];
            v += __shfl_xor(v, 1);
            v += __shfl_xor(v, 2);
            v += __shfl_xor(v, 4);
            v += __shfl_xor(v, 8);
            if (r0 == 0) {
                int row = qb * 256 + wv * 64 + m * 16 + hi * 4 + q;
                atomicAdd(&Ssum[row], v);
            }
        }
    }
}

// ---- kernel 4: per-row term = log(S - PADROWS) - true_logit ----
// Kn fragment-major: row lab, byte b=4*lane at
// (lab>>5)*8192 + ((lab>>4)&1)*4096 + (lane>>4)*1024 + ((lane>>2)&3)*256 + (lab&15)*16 + (lane&3)*4
__global__ void term_kernel(const __hip_bfloat16* __restrict__ Qn,
                            const char* __restrict__ Kn,
                            const int* __restrict__ labels,
                            const float* __restrict__ Ssum,
                            float* __restrict__ T) {
    int w = (blockIdx.x * blockDim.x + threadIdx.x) >> 6;
    int lane = threadIdx.x & 63;
    if (w >= N_) return;
    int lab = labels[w];
    __hip_bfloat162 q2 = ((const __hip_bfloat162*)(Qn + (size_t)w * D_))[lane];
    const char* kaddr = Kn + ((size_t)(lab >> 5)) * 8192 + ((lab >> 4) & 1) * 4096
                      + (lane >> 4) * 1024 + ((lane >> 2) & 3) * 256
                      + (lab & 15) * 16 + (lane & 3) * 4;
    __hip_bfloat162 k2 = *(const __hip_bfloat162*)kaddr;
    float d = __bfloat162float(q2.x) * __bfloat162float(k2.x)
            + __bfloat162float(q2.y) * __bfloat162float(k2.y);
    #pragma unroll
    for (int off = 32; off; off >>= 1) d += __shfl_xor(d, off);
    if (lane == 0) T[w] = logf(Ssum[w] - PADROWS_) - d * LN2_;
}

// ---- kernel 5: mean over N ----
__global__ void reduce_kernel(const float* __restrict__ T, float* __restrict__ out) {
    __shared__ float sm[4];
    float s = 0.f;
    for (int i = threadIdx.x; i < N_; i += 256) s += T[i];
    #pragma unroll
    for (int off = 32; off; off >>= 1) s += __shfl_xor(s, off);
    if ((threadIdx.x & 63) == 0) sm[threadIdx.x >> 6] = s;
    __syncthreads();
    if (threadIdx.x == 0) out[0] = (sm[0] + sm[1] + sm[2] + sm[3]) * (1.0f / (float)N_);
}

extern "C" void kernel_launch(void* const* d_in, const int* in_sizes, int n_in,
                              void* d_out, int out_size, void* d_ws, size_t ws_size,
                              hipStream_t stream) {
    (void)in_sizes; (void)n_in; (void)out_size; (void)ws_size;
    const float* Q   = (const float*)d_in[0];
    const float* K   = (const float*)d_in[1];
    const int* loc   = (const int*)d_in[2];
    const int* labels= (const int*)d_in[3];
    float* out = (float*)d_out;

    char* ws = (char*)d_ws;
    char* Kn           = ws;                                        // 3136*8192 = 25,690,112 B
    __hip_bfloat16* Qn = (__hip_bfloat16*)(ws + 25690112);          // N_*128*2  =  1,048,576 B
    float* Ssum        = (float*)(ws + 25690112 + 1048576);         // N_*4
    float* T           = Ssum + N_;                                  // N_*4

    knorm_kernel<<<VSTRIPS_, 256, 0, stream>>>(K, Kn);
    qnorm_kernel<<<N_ / 4, 256, 0, stream>>>(Q, loc, Qn, Ssum);
    ce_main<<<dim3(16, NPHASE_), 256, 0, stream>>>(Qn, Kn, Ssum);
    term_kernel<<<N_ / 4, 256, 0, stream>>>(Qn, Kn, labels, Ssum, T);
    reduce_kernel<<<1, 256, 0, stream>>>(T, out);
}

// Round 14
// 116.805 us; speedup vs baseline: 7.7472x; 1.0029x over previous
//
#include <hip/hip_runtime.h>
#include <hip/hip_bf16.h>

#define S_ 1024
#define D_ 128
#define V_ 100000
#define VSTRIPS_ 3136   // 32-row v-strips; 3125 valid (=100000), 11 zero pads
#define NPHASE_ 32      // 32 phases x 98 strips = 3136
#define N_ 4096
#define PADROWS_ 352.0f

typedef __attribute__((ext_vector_type(4))) float f32x4;
typedef __attribute__((ext_vector_type(8))) short bf16x8;

#define LOG2E_ 1.4426950408889634f
#define LN2_   0.6931471805599453f

__device__ __forceinline__ float exp2_fast(float x) {
#if __has_builtin(__builtin_amdgcn_exp2f)
    return __builtin_amdgcn_exp2f(x);
#else
    return exp2f(x);
#endif
}

// ---- kernel 1: normalize K -> bf16 in FRAGMENT-MAJOR layout (16x16x32) ----
// Strip s (32 rows) occupies 8KB: frag f=nn*4+kk (1KB each), lane l holds
// row nn*16+(l&15), k-bytes kk*64+(l>>4)*16. ce_main loads B operands with
// perfectly coalesced dwordx4 (no LDS anywhere downstream).
__global__ void knorm_kernel(const float* __restrict__ K, char* __restrict__ Kn) {
    __shared__ char sm[8192];
    const int strip = blockIdx.x;
    const int tid = threadIdx.x;
    const int lane = tid & 63;
    const int wvv = tid >> 6;
    char* dst = Kn + (size_t)strip * 8192;
    if (strip >= 3125) {                       // zero pad strip
        const f32x4 z = {0.f, 0.f, 0.f, 0.f};
        *(f32x4*)(dst + tid * 32) = z;
        *(f32x4*)(dst + tid * 32 + 16) = z;
        return;
    }
    #pragma unroll
    for (int i = 0; i < 8; ++i) {
        int r = wvv * 8 + i;
        float2 v = ((const float2*)(K + ((size_t)strip * 32 + r) * D_))[lane];
        float ss = v.x * v.x + v.y * v.y;
        #pragma unroll
        for (int off = 32; off; off >>= 1) ss += __shfl_xor(ss, off);
        float rn = rsqrtf(ss);
        __hip_bfloat162 o;
        o.x = __float2bfloat16(v.x * rn);
        o.y = __float2bfloat16(v.y * rn);
        int addr = (r >> 4) * 4096 + (lane >> 4) * 1024 + ((lane >> 2) & 3) * 256
                 + (r & 15) * 16 + (lane & 3) * 4;
        *(__hip_bfloat162*)(sm + addr) = o;
    }
    __syncthreads();
    *(f32x4*)(dst + tid * 32)      = *(const f32x4*)(sm + tid * 32);
    *(f32x4*)(dst + tid * 32 + 16) = *(const f32x4*)(sm + tid * 32 + 16);
}

// ---- kernel 2: gather + normalize Q -> bf16 row-major (pre-scaled log2 e); zero Ssum ----
__global__ void qnorm_kernel(const float* __restrict__ Q, const int* __restrict__ loc,
                             __hip_bfloat16* __restrict__ Qn, float* __restrict__ Ssum) {
    int w = (blockIdx.x * blockDim.x + threadIdx.x) >> 6;
    int lane = threadIdx.x & 63;
    if (w >= N_) return;
    if (lane == 0) Ssum[w] = 0.f;
    int b = loc[2 * w], s = loc[2 * w + 1];
    float2 v = ((const float2*)(Q + ((size_t)b * S_ + (size_t)s) * D_))[lane];
    float ss = v.x * v.x + v.y * v.y;
    #pragma unroll
    for (int off = 32; off; off >>= 1) ss += __shfl_xor(ss, off);
    float rn = rsqrtf(ss) * LOG2E_;        // exp2 domain
    __hip_bfloat162 o;
    o.x = __float2bfloat16(v.x * rn);
    o.y = __float2bfloat16(v.y * rn);
    ((__hip_bfloat162*)(Qn + (size_t)w * D_))[lane] = o;
}

// ---- kernel 3: main  sum_v exp2(q . k_v)  -- NO LDS, NO BARRIERS ----
// R10 structure (grid 512 = 2 blocks/CU); the one change: MFMA and exp2 are
// INTERLEAVED per kk-group and pinned with sched_barrier(0) so each wave
// feeds the matrix pipe and the trans pipe concurrently (in-order issue was
// serializing the two bursts; MfmaUtil+VALUBusy summed to ~wall every round).
__global__ __launch_bounds__(256, 2) void ce_main(
    const __hip_bfloat16* __restrict__ Qn,
    const char* __restrict__ Kn,
    float* __restrict__ Ssum)
{
    const int tid  = threadIdx.x;
    const int lane = tid & 63;
    const int wv   = tid >> 6;
    const int r0   = lane & 15;
    const int hi   = lane >> 4;          // 0..3

    // grid (16,32): XCD owns 4 whole phase-groups (all 16 q-blocks of each)
    const int fid   = blockIdx.y * 16 + blockIdx.x;
    const int xcd   = fid & 7;
    const int idx   = fid >> 3;          // 0..63
    const int phase = xcd * 4 + (idx >> 4);   // 0..31
    const int qb    = idx & 15;          // 0..15 (256 q-rows each)

    // ---- Q fragments -> registers (loop-invariant) ----
    bf16x8 afr[4][4];
    {
        const char* qsrc = (const char*)Qn + ((size_t)qb * 256 + wv * 64 + r0) * 256
                         + (hi << 4);
        #pragma unroll
        for (int m = 0; m < 4; ++m)
            #pragma unroll
            for (int kk = 0; kk < 4; ++kk)
                afr[m][kk] = *(const bf16x8*)(qsrc + m * 4096 + kk * 64);
    }

    // strip j (j=0..97) -> global strip phase + NPHASE_*j
    const char* kvbase = Kn + (size_t)phase * 8192 + (lane << 4);

#define LOADSET(R, j) do {                                                   \
        const char* p  = kvbase + (size_t)(j) * (8192 * NPHASE_);            \
        const char* p2 = p + 4096;                                           \
        R[0] = *(const bf16x8*)(p);         R[1] = *(const bf16x8*)(p + 1024); \
        R[2] = *(const bf16x8*)(p + 2048);  R[3] = *(const bf16x8*)(p + 3072); \
        R[4] = *(const bf16x8*)(p2);        R[5] = *(const bf16x8*)(p2 + 1024);\
        R[6] = *(const bf16x8*)(p2 + 2048); R[7] = *(const bf16x8*)(p2 + 3072);\
    } while (0)

    // Interleaved: per kk-group, 8 MFMA (strip j) then 8 exp2 + 8 fadd of the
    // PREVIOUS strip's acc quarter m=kk. sched_barrier(0) pins the pattern.
#define COMPUTE_ILV(R, ACC, PRV) do {                                        \
        __builtin_amdgcn_s_setprio(1);                                       \
        _Pragma("unroll")                                                    \
        for (int m = 0; m < 4; ++m) {                                        \
            ACC[m][0] = __builtin_amdgcn_mfma_f32_16x16x32_bf16(afr[m][0], R[0], fz, 0, 0, 0); \
            ACC[m][1] = __builtin_amdgcn_mfma_f32_16x16x32_bf16(afr[m][0], R[4], fz, 0, 0, 0); \
        }                                                                    \
        __builtin_amdgcn_s_setprio(0);                                       \
        __builtin_amdgcn_sched_barrier(0);                                   \
        _Pragma("unroll")                                                    \
        for (int q = 0; q < 4; ++q)                                          \
            psum[0][q] += exp2_fast(PRV[0][0][q]) + exp2_fast(PRV[0][1][q]); \
        __builtin_amdgcn_sched_barrier(0);                                   \
        _Pragma("unroll")                                                    \
        for (int kk = 1; kk < 4; ++kk) {                                     \
            __builtin_amdgcn_s_setprio(1);                                   \
            _Pragma("unroll")                                                \
            for (int m = 0; m < 4; ++m) {                                    \
                ACC[m][0] = __builtin_amdgcn_mfma_f32_16x16x32_bf16(afr[m][kk], R[kk],     ACC[m][0], 0, 0, 0); \
                ACC[m][1] = __builtin_amdgcn_mfma_f32_16x16x32_bf16(afr[m][kk], R[4 + kk], ACC[m][1], 0, 0, 0); \
            }                                                                \
            __builtin_amdgcn_s_setprio(0);                                   \
            __builtin_amdgcn_sched_barrier(0);                               \
            _Pragma("unroll")                                                \
            for (int q = 0; q < 4; ++q)                                      \
                psum[kk][q] += exp2_fast(PRV[kk][0][q]) + exp2_fast(PRV[kk][1][q]); \
            __builtin_amdgcn_sched_barrier(0);                               \
        }                                                                    \
    } while (0)

#define EXP2S(ACC) do {                                                      \
        _Pragma("unroll")                                                    \
        for (int m = 0; m < 4; ++m)                                          \
            _Pragma("unroll")                                                \
            for (int q = 0; q < 4; ++q)                                      \
                psum[m][q] += exp2_fast(ACC[m][0][q]) + exp2_fast(ACC[m][1][q]); \
    } while (0)

    float psum[4][4];
    #pragma unroll
    for (int m = 0; m < 4; ++m)
        #pragma unroll
        for (int q = 0; q < 4; ++q) psum[m][q] = 0.f;

    const f32x4 fz = {0.f, 0.f, 0.f, 0.f};
    f32x4 accE[4][2], accO[4][2];
    #pragma unroll
    for (int m = 0; m < 4; ++m)
        #pragma unroll
        for (int nn = 0; nn < 2; ++nn)
            accO[m][nn] = (f32x4){-16384.f, -16384.f, -16384.f, -16384.f}; // exp2 -> 0

    bf16x8 RA[8], RB[8];
    LOADSET(RA, 0);
    #pragma unroll 1
    for (int j = 0; j < 96; j += 2) {
        LOADSET(RB, j + 1);              // prefetch next strip
        COMPUTE_ILV(RA, accE, accO);     // MFMA strip j  ||  exp2 strip j-1
        LOADSET(RA, j + 2);
        COMPUTE_ILV(RB, accO, accE);     // MFMA strip j+1 || exp2 strip j
    }
    // epilogue: strips 96 (RA already loaded), 97
    LOADSET(RB, 97);
    COMPUTE_ILV(RA, accE, accO);         // strip 96 || exp2 95
    COMPUTE_ILV(RB, accO, accE);         // strip 97 || exp2 96
    EXP2S(accO);                         // strip 97 tail

#undef LOADSET
#undef COMPUTE_ILV
#undef EXP2S

    // reduce over 16 lanes (same q-rows, different v-cols), then atomics
    #pragma unroll
    for (int m = 0; m < 4; ++m) {
        #pragma unroll
        for (int q = 0; q < 4; ++q) {
            float v = psum[m][q];
            v += __shfl_xor(v, 1);
            v += __shfl_xor(v, 2);
            v += __shfl_xor(v, 4);
            v += __shfl_xor(v, 8);
            if (r0 == 0) {
                int row = qb * 256 + wv * 64 + m * 16 + hi * 4 + q;
                atomicAdd(&Ssum[row], v);
            }
        }
    }
}

// ---- kernel 4: per-row term = log(S - PADROWS) - true_logit ----
// Kn fragment-major: row lab, byte b=4*lane at
// (lab>>5)*8192 + ((lab>>4)&1)*4096 + (lane>>4)*1024 + ((lane>>2)&3)*256 + (lab&15)*16 + (lane&3)*4
__global__ void term_kernel(const __hip_bfloat16* __restrict__ Qn,
                            const char* __restrict__ Kn,
                            const int* __restrict__ labels,
                            const float* __restrict__ Ssum,
                            float* __restrict__ T) {
    int w = (blockIdx.x * blockDim.x + threadIdx.x) >> 6;
    int lane = threadIdx.x & 63;
    if (w >= N_) return;
    int lab = labels[w];
    __hip_bfloat162 q2 = ((const __hip_bfloat162*)(Qn + (size_t)w * D_))[lane];
    const char* kaddr = Kn + ((size_t)(lab >> 5)) * 8192 + ((lab >> 4) & 1) * 4096
                      + (lane >> 4) * 1024 + ((lane >> 2) & 3) * 256
                      + (lab & 15) * 16 + (lane & 3) * 4;
    __hip_bfloat162 k2 = *(const __hip_bfloat162*)kaddr;
    float d = __bfloat162float(q2.x) * __bfloat162float(k2.x)
            + __bfloat162float(q2.y) * __bfloat162float(k2.y);
    #pragma unroll
    for (int off = 32; off; off >>= 1) d += __shfl_xor(d, off);
    if (lane == 0) T[w] = logf(Ssum[w] - PADROWS_) - d * LN2_;
}

// ---- kernel 5: mean over N ----
__global__ void reduce_kernel(const float* __restrict__ T, float* __restrict__ out) {
    __shared__ float sm[4];
    float s = 0.f;
    for (int i = threadIdx.x; i < N_; i += 256) s += T[i];
    #pragma unroll
    for (int off = 32; off; off >>= 1) s += __shfl_xor(s, off);
    if ((threadIdx.x & 63) == 0) sm[threadIdx.x >> 6] = s;
    __syncthreads();
    if (threadIdx.x == 0) out[0] = (sm[0] + sm[1] + sm[2] + sm[3]) * (1.0f / (float)N_);
}

extern "C" void kernel_launch(void* const* d_in, const int* in_sizes, int n_in,
                              void* d_out, int out_size, void* d_ws, size_t ws_size,
                              hipStream_t stream) {
    (void)in_sizes; (void)n_in; (void)out_size; (void)ws_size;
    const float* Q   = (const float*)d_in[0];
    const float* K   = (const float*)d_in[1];
    const int* loc   = (const int*)d_in[2];
    const int* labels= (const int*)d_in[3];
    float* out = (float*)d_out;

    char* ws = (char*)d_ws;
    char* Kn           = ws;                                        // 3136*8192 = 25,690,112 B
    __hip_bfloat16* Qn = (__hip_bfloat16*)(ws + 25690112);          // N_*128*2  =  1,048,576 B
    float* Ssum        = (float*)(ws + 25690112 + 1048576);         // N_*4
    float* T           = Ssum + N_;                                  // N_*4

    knorm_kernel<<<VSTRIPS_, 256, 0, stream>>>(K, Kn);
    qnorm_kernel<<<N_ / 4, 256, 0, stream>>>(Q, loc, Qn, Ssum);
    ce_main<<<dim3(16, NPHASE_), 256, 0, stream>>>(Qn, Kn, Ssum);
    term_kernel<<<N_ / 4, 256, 0, stream>>>(Qn, Kn, labels, Ssum, T);
    reduce_kernel<<<1, 256, 0, stream>>>(T, out);
}

// Round 15
// 86.499 us; speedup vs baseline: 10.4616x; 1.3504x over previous
//
#include <hip/hip_runtime.h>
#include <hip/hip_bf16.h>
#include <hip/hip_fp8.h>

#define S_ 1024
#define D_ 128
#define V_ 100000
#define VSTRIPS_ 3136   // 32-row v-strips; 3125 valid (=100000), 11 zero pads
#define NPHASE_ 32      // 32 phases x 98 strips = 3136
#define N_ 4096
#define PADROWS_ 352.0f

typedef __attribute__((ext_vector_type(4))) float f32x4;
typedef __attribute__((ext_vector_type(4))) int   i32x4;
typedef __attribute__((ext_vector_type(8))) int   i32x8;

#define LOG2E_ 1.4426950408889634f
#define LN2_   0.6931471805599453f

__device__ __forceinline__ float exp2_fast(float x) {
#if __has_builtin(__builtin_amdgcn_exp2f)
    return __builtin_amdgcn_exp2f(x);
#else
    return exp2f(x);
#endif
}

__device__ __forceinline__ unsigned char to_fp8(float x) {
    __hip_fp8_e4m3 t(x);
    return (unsigned char)t.__x;
}
__device__ __forceinline__ float from_fp8(unsigned char b) {
    __hip_fp8_e4m3 t; t.__x = (__hip_fp8_storage_t)b;
    return (float)t;
}

// ---- kernel 1: normalize K -> fp8 e4m3, FRAGMENT-MAJOR for mfma 16x16x128 ----
// Strip s (32 v-rows) = 4KB. B-lane l: col=l&15 (within nn-half), k-bytes =
// (l>>4)*32 + [0..31], split in two 16B halves at +0 / +1024.
// Element (r,k): addr = (r>>4)*2048 + ((k&31)>>4)*1024 + ((k>>5)*16+(r&15))*16 + (k&15)
__global__ void knorm_kernel(const float* __restrict__ K, char* __restrict__ Kn) {
    __shared__ char sm[4096];
    const int strip = blockIdx.x;
    const int tid = threadIdx.x;
    const int lane = tid & 63;
    const int wvv = tid >> 6;
    char* dst = Kn + (size_t)strip * 4096;
    if (strip >= 3125) {                       // zero pad strip: fp8 0x00 = 0.0
        *(f32x4*)(dst + tid * 16) = (f32x4){0.f, 0.f, 0.f, 0.f};
        return;
    }
    #pragma unroll
    for (int i = 0; i < 8; ++i) {
        int r = wvv * 8 + i;
        float2 v = ((const float2*)(K + ((size_t)strip * 32 + r) * D_))[lane];
        float ss = v.x * v.x + v.y * v.y;
        #pragma unroll
        for (int off = 32; off; off >>= 1) ss += __shfl_xor(ss, off);
        float rn = rsqrtf(ss);
        // k = 2*lane, 2*lane+1
        unsigned short pk = (unsigned short)to_fp8(v.x * rn)
                          | ((unsigned short)to_fp8(v.y * rn) << 8);
        int addr = ((r >> 4) << 11) + (((lane >> 3) & 1) << 10)
                 + (((lane >> 4) * 16 + (r & 15)) << 4) + ((lane & 7) << 1);
        *(unsigned short*)(sm + addr) = pk;
    }
    __syncthreads();
    *(f32x4*)(dst + tid * 16) = *(const f32x4*)(sm + tid * 16);
}

// ---- kernel 2: gather + normalize Q -> fp8 row-major (pre-scaled log2 e); zero Ssum ----
__global__ void qnorm_kernel(const float* __restrict__ Q, const int* __restrict__ loc,
                             char* __restrict__ Qn, float* __restrict__ Ssum) {
    int w = (blockIdx.x * blockDim.x + threadIdx.x) >> 6;
    int lane = threadIdx.x & 63;
    if (w >= N_) return;
    if (lane == 0) Ssum[w] = 0.f;
    int b = loc[2 * w], s = loc[2 * w + 1];
    float2 v = ((const float2*)(Q + ((size_t)b * S_ + (size_t)s) * D_))[lane];
    float ss = v.x * v.x + v.y * v.y;
    #pragma unroll
    for (int off = 32; off; off >>= 1) ss += __shfl_xor(ss, off);
    float rn = rsqrtf(ss) * LOG2E_;        // exp2 domain
    unsigned short pk = (unsigned short)to_fp8(v.x * rn)
                      | ((unsigned short)to_fp8(v.y * rn) << 8);
    *(unsigned short*)(Qn + (size_t)w * 128 + 2 * lane) = pk;
}

// ---- kernel 3: main  sum_v exp2(q . k_v)  -- MX-fp8 K=128, NO LDS, NO BARRIERS ----
// mfma_scale_f32_16x16x128_f8f6f4, scales=127 (E8M0 2^0) -> plain e4m3 matmul,
// 2x the bf16 MFMA rate, K=128 per instruction (no acc chains). Wave: 32q x 32v
// (m=2, nn=2 -> 4 MFMA + 16 exp2 per strip). grid (32,32) = 4 blocks/CU.
// Register double-buffer one strip ahead; exp2 of previous strip deferred.
__global__ __launch_bounds__(256, 2) void ce_main(
    const char* __restrict__ Qn,
    const char* __restrict__ Kn,
    float* __restrict__ Ssum)
{
    const int tid  = threadIdx.x;
    const int lane = tid & 63;
    const int wv   = tid >> 6;
    const int r0   = lane & 15;
    const int hi   = lane >> 4;          // 0..3

    // grid (32,32): XCD owns 4 whole phase-groups (all 32 q-blocks of each)
    const int fid   = blockIdx.y * 32 + blockIdx.x;
    const int xcd   = fid & 7;
    const int idx   = fid >> 3;              // 0..127
    const int phase = xcd * 4 + (idx >> 5);  // 0..31
    const int qb    = idx & 31;              // 0..31 (128 q-rows each)

    // ---- Q fragments (fp8) -> registers ----
    // A-lane l: row = l&15, k-bytes (l>>4)*32 + [0..31] from row-major Qn
    i32x8 afr[2];
    {
        const char* qsrc = Qn + ((size_t)qb * 128 + wv * 32 + r0) * 128 + (hi << 5);
        #pragma unroll
        for (int m = 0; m < 2; ++m) {
            i32x4 lo = *(const i32x4*)(qsrc + m * 2048);
            i32x4 hh = *(const i32x4*)(qsrc + m * 2048 + 16);
            afr[m] = (i32x8){lo[0], lo[1], lo[2], lo[3], hh[0], hh[1], hh[2], hh[3]};
        }
    }

    // strip j (0..97) at phase + NPHASE_*j; per-lane base + imm offsets
    const char* kvbase = Kn + (size_t)phase * 4096 + (lane << 4);

#define LOADSET(B0, B1, j) do {                                              \
        const char* p = kvbase + (size_t)(j) * (4096 * NPHASE_);             \
        i32x4 t0 = *(const i32x4*)(p);                                       \
        i32x4 t1 = *(const i32x4*)(p + 1024);                                \
        i32x4 t2 = *(const i32x4*)(p + 2048);                                \
        i32x4 t3 = *(const i32x4*)(p + 3072);                                \
        B0 = (i32x8){t0[0], t0[1], t0[2], t0[3], t1[0], t1[1], t1[2], t1[3]};\
        B1 = (i32x8){t2[0], t2[1], t2[2], t2[3], t3[0], t3[1], t3[2], t3[3]};\
    } while (0)

#define COMPUTE(B0, B1, ACC) do {                                            \
        __builtin_amdgcn_s_setprio(1);                                       \
        ACC[0][0] = __builtin_amdgcn_mfma_scale_f32_16x16x128_f8f6f4(        \
            afr[0], B0, fz, 0, 0, 0, 127, 0, 127);                           \
        ACC[0][1] = __builtin_amdgcn_mfma_scale_f32_16x16x128_f8f6f4(        \
            afr[0], B1, fz, 0, 0, 0, 127, 0, 127);                           \
        ACC[1][0] = __builtin_amdgcn_mfma_scale_f32_16x16x128_f8f6f4(        \
            afr[1], B0, fz, 0, 0, 0, 127, 0, 127);                           \
        ACC[1][1] = __builtin_amdgcn_mfma_scale_f32_16x16x128_f8f6f4(        \
            afr[1], B1, fz, 0, 0, 0, 127, 0, 127);                           \
        __builtin_amdgcn_s_setprio(0);                                       \
    } while (0)

#define EXP2S(ACC) do {                                                      \
        _Pragma("unroll")                                                    \
        for (int m = 0; m < 2; ++m)                                          \
            _Pragma("unroll")                                                \
            for (int q = 0; q < 4; ++q)                                      \
                psum[m][q] += exp2_fast(ACC[m][0][q]) + exp2_fast(ACC[m][1][q]); \
    } while (0)

    float psum[2][4];
    #pragma unroll
    for (int m = 0; m < 2; ++m)
        #pragma unroll
        for (int q = 0; q < 4; ++q) psum[m][q] = 0.f;

    const f32x4 fz = {0.f, 0.f, 0.f, 0.f};
    f32x4 accE[2][2], accO[2][2];
    #pragma unroll
    for (int m = 0; m < 2; ++m)
        #pragma unroll
        for (int nn = 0; nn < 2; ++nn)
            accO[m][nn] = (f32x4){-16384.f, -16384.f, -16384.f, -16384.f}; // exp2 -> 0

    i32x8 RA0, RA1, RB0, RB1;
    LOADSET(RA0, RA1, 0);
    #pragma unroll 1
    for (int j = 0; j < 96; j += 2) {
        LOADSET(RB0, RB1, j + 1);        // prefetch next strip
        EXP2S(accO);                     // strip j-1 exp2 under load latency
        COMPUTE(RA0, RA1, accE);         // strip j
        LOADSET(RA0, RA1, j + 2);
        EXP2S(accE);                     // strip j
        COMPUTE(RB0, RB1, accO);         // strip j+1
    }
    // epilogue: strips 96 (already in RA), 97
    LOADSET(RB0, RB1, 97);
    EXP2S(accO);                         // strip 95
    COMPUTE(RA0, RA1, accE);             // strip 96
    EXP2S(accE);                         // strip 96
    COMPUTE(RB0, RB1, accO);             // strip 97
    EXP2S(accO);                         // strip 97

#undef LOADSET
#undef COMPUTE
#undef EXP2S

    // C/D 16x16: col=lane&15 (v), row=hi*4+reg (q). Reduce over v-cols, atomics.
    #pragma unroll
    for (int m = 0; m < 2; ++m) {
        #pragma unroll
        for (int q = 0; q < 4; ++q) {
            float v = psum[m][q];
            v += __shfl_xor(v, 1);
            v += __shfl_xor(v, 2);
            v += __shfl_xor(v, 4);
            v += __shfl_xor(v, 8);
            if (r0 == 0) {
                int row = qb * 128 + wv * 32 + m * 16 + hi * 4 + q;
                atomicAdd(&Ssum[row], v);
            }
        }
    }
}

// ---- kernel 4: per-row term = log(S - PADROWS) - true_logit ----
// Kn fragment-major fp8: row lab, k=2*lane:
// addr = (lab>>5)*4096 + ((lab>>4)&1)*2048 + ((lane>>3)&1)*1024
//      + ((lane>>4)*16 + (lab&15))*16 + 2*(lane&7)
__global__ void term_kernel(const char* __restrict__ Qn,
                            const char* __restrict__ Kn,
                            const int* __restrict__ labels,
                            const float* __restrict__ Ssum,
                            float* __restrict__ T) {
    int w = (blockIdx.x * blockDim.x + threadIdx.x) >> 6;
    int lane = threadIdx.x & 63;
    if (w >= N_) return;
    int lab = labels[w];
    const unsigned char* qp = (const unsigned char*)(Qn + (size_t)w * 128 + 2 * lane);
    const unsigned char* kp = (const unsigned char*)(Kn
                      + ((size_t)(lab >> 5)) * 4096 + (((lab >> 4) & 1) << 11)
                      + (((lane >> 3) & 1) << 10)
                      + (((lane >> 4) * 16 + (lab & 15)) << 4) + ((lane & 7) << 1));
    float d = from_fp8(qp[0]) * from_fp8(kp[0])
            + from_fp8(qp[1]) * from_fp8(kp[1]);
    #pragma unroll
    for (int off = 32; off; off >>= 1) d += __shfl_xor(d, off);
    if (lane == 0) T[w] = logf(Ssum[w] - PADROWS_) - d * LN2_;
}

// ---- kernel 5: mean over N ----
__global__ void reduce_kernel(const float* __restrict__ T, float* __restrict__ out) {
    __shared__ float sm[4];
    float s = 0.f;
    for (int i = threadIdx.x; i < N_; i += 256) s += T[i];
    #pragma unroll
    for (int off = 32; off; off >>= 1) s += __shfl_xor(s, off);
    if ((threadIdx.x & 63) == 0) sm[threadIdx.x >> 6] = s;
    __syncthreads();
    if (threadIdx.x == 0) out[0] = (sm[0] + sm[1] + sm[2] + sm[3]) * (1.0f / (float)N_);
}

extern "C" void kernel_launch(void* const* d_in, const int* in_sizes, int n_in,
                              void* d_out, int out_size, void* d_ws, size_t ws_size,
                              hipStream_t stream) {
    (void)in_sizes; (void)n_in; (void)out_size; (void)ws_size;
    const float* Q   = (const float*)d_in[0];
    const float* K   = (const float*)d_in[1];
    const int* loc   = (const int*)d_in[2];
    const int* labels= (const int*)d_in[3];
    float* out = (float*)d_out;

    char* ws = (char*)d_ws;
    char* Kn    = ws;                                   // 3136*4096 = 12,845,056 B
    char* Qn    = ws + 12845056;                        // N_*128    =     524,288 B
    float* Ssum = (float*)(ws + 12845056 + 524288);     // N_*4
    float* T    = Ssum + N_;                            // N_*4

    knorm_kernel<<<VSTRIPS_, 256, 0, stream>>>(K, Kn);
    qnorm_kernel<<<N_ / 4, 256, 0, stream>>>(Q, loc, Qn, Ssum);
    ce_main<<<dim3(32, NPHASE_), 256, 0, stream>>>(Qn, Kn, Ssum);
    term_kernel<<<N_ / 4, 256, 0, stream>>>(Qn, Kn, labels, Ssum, T);
    reduce_kernel<<<1, 256, 0, stream>>>(T, out);
}

// Round 16
// 83.865 us; speedup vs baseline: 10.7901x; 1.0314x over previous
//
#include <hip/hip_runtime.h>
#include <hip/hip_bf16.h>
#include <hip/hip_fp8.h>

#define S_ 1024
#define D_ 128
#define V_ 100000
#define VSTRIPS_ 3136   // 32-row v-strips; 3125 valid (=100000), 11 zero pads
#define NPHASE_ 32      // 32 phases x 98 strips = 3136
#define N_ 4096
#define PADROWS_ 352.0f

typedef __attribute__((ext_vector_type(4))) float f32x4;
typedef __attribute__((ext_vector_type(4))) int   i32x4;
typedef __attribute__((ext_vector_type(8))) int   i32x8;

#define LOG2E_ 1.4426950408889634f
#define LN2_   0.6931471805599453f

__device__ __forceinline__ float exp2_fast(float x) {
#if __has_builtin(__builtin_amdgcn_exp2f)
    return __builtin_amdgcn_exp2f(x);
#else
    return exp2f(x);
#endif
}

__device__ __forceinline__ unsigned char to_fp8(float x) {
    __hip_fp8_e4m3 t(x);
    return (unsigned char)t.__x;
}
__device__ __forceinline__ float from_fp8(unsigned char b) {
    __hip_fp8_e4m3 t; t.__x = (__hip_fp8_storage_t)b;
    return (float)t;
}

// ---- kernel 1: prep = knorm (fragment-major fp8 Kn) + qnorm (row-major fp8 Qn) ----
// Kn strip layout (CONTIGUOUS 32B per MFMA lane): strip = 4KB,
//   element (r local, k): addr = (r>>4)*2048 + ((k>>5)*16 + (r&15))*32 + (k&31)
// -> B-operand read for nn-half: addr = nn*2048 + lane*32 + [0..31] (one i32x8).
__global__ void prep_kernel(const float* __restrict__ K, const float* __restrict__ Q,
                            const int* __restrict__ loc,
                            char* __restrict__ Kn, char* __restrict__ Qn,
                            float* __restrict__ Ssum) {
    __shared__ char sm[4096];
    const int bid = blockIdx.x;
    const int tid = threadIdx.x;
    const int lane = tid & 63;
    const int wvv = tid >> 6;
    if (bid < VSTRIPS_) {                      // ---- K strip ----
        char* dst = Kn + (size_t)bid * 4096;
        if (bid >= 3125) {                     // zero pad strip: fp8 0x00 = 0.0
            *(f32x4*)(dst + tid * 16) = (f32x4){0.f, 0.f, 0.f, 0.f};
            return;
        }
        #pragma unroll
        for (int i = 0; i < 8; ++i) {
            int r = wvv * 8 + i;
            float2 v = ((const float2*)(K + ((size_t)bid * 32 + r) * D_))[lane];
            float ss = v.x * v.x + v.y * v.y;
            #pragma unroll
            for (int off = 32; off; off >>= 1) ss += __shfl_xor(ss, off);
            float rn = rsqrtf(ss);
            // k = 2*lane, 2*lane+1: k>>5 = lane>>4, k&31 = 2*(lane&15)
            unsigned short pk = (unsigned short)to_fp8(v.x * rn)
                              | ((unsigned short)to_fp8(v.y * rn) << 8);
            int addr = ((r >> 4) << 11) + (((lane >> 4) * 16 + (r & 15)) << 5)
                     + ((lane & 15) << 1);
            *(unsigned short*)(sm + addr) = pk;
        }
        __syncthreads();
        *(f32x4*)(dst + tid * 16) = *(const f32x4*)(sm + tid * 16);
    } else {                                   // ---- Q rows (4 per block) ----
        int w = (bid - VSTRIPS_) * 4 + wvv;
        if (lane == 0) Ssum[w] = 0.f;
        int b = loc[2 * w], s = loc[2 * w + 1];
        float2 v = ((const float2*)(Q + ((size_t)b * S_ + (size_t)s) * D_))[lane];
        float ss = v.x * v.x + v.y * v.y;
        #pragma unroll
        for (int off = 32; off; off >>= 1) ss += __shfl_xor(ss, off);
        float rn = rsqrtf(ss) * LOG2E_;        // exp2 domain
        unsigned short pk = (unsigned short)to_fp8(v.x * rn)
                          | ((unsigned short)to_fp8(v.y * rn) << 8);
        *(unsigned short*)(Qn + (size_t)w * 128 + 2 * lane) = pk;
    }
}

// ---- kernel 2: main  sum_v exp2(q . k_v)  -- MX-fp8 K=128, NO LDS, NO BARRIERS ----
// mfma_scale_f32_16x16x128_f8f6f4, scales=127 (E8M0 2^0) -> plain e4m3 matmul.
// Wave: 32q x 32v (m=2, nn=2 -> 4 MFMA + 16 exp2 per strip). grid (32,32).
// All operand loads are single i32x8 (32B contiguous/lane) -> zero repack movs.
__global__ __launch_bounds__(256, 2) void ce_main(
    const char* __restrict__ Qn,
    const char* __restrict__ Kn,
    float* __restrict__ Ssum)
{
    const int tid  = threadIdx.x;
    const int lane = tid & 63;
    const int wv   = tid >> 6;
    const int r0   = lane & 15;
    const int hi   = lane >> 4;          // 0..3

    // grid (32,32): XCD owns 4 whole phase-groups (all 32 q-blocks of each)
    const int fid   = blockIdx.y * 32 + blockIdx.x;
    const int xcd   = fid & 7;
    const int idx   = fid >> 3;              // 0..127
    const int phase = xcd * 4 + (idx >> 5);  // 0..31
    const int qb    = idx & 31;              // 0..31 (128 q-rows each)

    // ---- Q fragments (fp8) -> registers: row=lane&15, k-bytes (lane>>4)*32 ----
    i32x8 afr[2];
    {
        const char* qsrc = Qn + ((size_t)qb * 128 + wv * 32 + r0) * 128 + (hi << 5);
        afr[0] = *(const i32x8*)(qsrc);
        afr[1] = *(const i32x8*)(qsrc + 2048);
    }

    // strip j (0..97) at phase + NPHASE_*j; operand = base + lane*32 (+2048 for nn=1)
    const char* kvbase = Kn + (size_t)phase * 4096 + (lane << 5);

#define LOADSET(B0, B1, j) do {                                              \
        const char* p = kvbase + (size_t)(j) * (4096 * NPHASE_);             \
        B0 = *(const i32x8*)(p);                                             \
        B1 = *(const i32x8*)(p + 2048);                                      \
    } while (0)

#define COMPUTE(B0, B1, ACC) do {                                            \
        __builtin_amdgcn_s_setprio(1);                                       \
        ACC[0][0] = __builtin_amdgcn_mfma_scale_f32_16x16x128_f8f6f4(        \
            afr[0], B0, fz, 0, 0, 0, 127, 0, 127);                           \
        ACC[0][1] = __builtin_amdgcn_mfma_scale_f32_16x16x128_f8f6f4(        \
            afr[0], B1, fz, 0, 0, 0, 127, 0, 127);                           \
        ACC[1][0] = __builtin_amdgcn_mfma_scale_f32_16x16x128_f8f6f4(        \
            afr[1], B0, fz, 0, 0, 0, 127, 0, 127);                           \
        ACC[1][1] = __builtin_amdgcn_mfma_scale_f32_16x16x128_f8f6f4(        \
            afr[1], B1, fz, 0, 0, 0, 127, 0, 127);                           \
        __builtin_amdgcn_s_setprio(0);                                       \
    } while (0)

#define EXP2S(ACC) do {                                                      \
        _Pragma("unroll")                                                    \
        for (int m = 0; m < 2; ++m)                                          \
            _Pragma("unroll")                                                \
            for (int q = 0; q < 4; ++q)                                      \
                psum[m][q] += exp2_fast(ACC[m][0][q]) + exp2_fast(ACC[m][1][q]); \
    } while (0)

    float psum[2][4];
    #pragma unroll
    for (int m = 0; m < 2; ++m)
        #pragma unroll
        for (int q = 0; q < 4; ++q) psum[m][q] = 0.f;

    const f32x4 fz = {0.f, 0.f, 0.f, 0.f};
    f32x4 accE[2][2], accO[2][2];
    #pragma unroll
    for (int m = 0; m < 2; ++m)
        #pragma unroll
        for (int nn = 0; nn < 2; ++nn)
            accO[m][nn] = (f32x4){-16384.f, -16384.f, -16384.f, -16384.f}; // exp2 -> 0

    i32x8 RA0, RA1, RB0, RB1;
    LOADSET(RA0, RA1, 0);
    #pragma unroll 1
    for (int j = 0; j < 96; j += 2) {
        LOADSET(RB0, RB1, j + 1);        // prefetch next strip
        EXP2S(accO);                     // strip j-1 exp2 under load latency
        COMPUTE(RA0, RA1, accE);         // strip j
        LOADSET(RA0, RA1, j + 2);
        EXP2S(accE);                     // strip j
        COMPUTE(RB0, RB1, accO);         // strip j+1
    }
    // epilogue: strips 96 (already in RA), 97
    LOADSET(RB0, RB1, 97);
    EXP2S(accO);                         // strip 95
    COMPUTE(RA0, RA1, accE);             // strip 96
    EXP2S(accE);                         // strip 96
    COMPUTE(RB0, RB1, accO);             // strip 97
    EXP2S(accO);                         // strip 97

#undef LOADSET
#undef COMPUTE
#undef EXP2S

    // C/D 16x16: col=lane&15 (v), row=hi*4+reg (q). Reduce over v-cols, atomics.
    #pragma unroll
    for (int m = 0; m < 2; ++m) {
        #pragma unroll
        for (int q = 0; q < 4; ++q) {
            float v = psum[m][q];
            v += __shfl_xor(v, 1);
            v += __shfl_xor(v, 2);
            v += __shfl_xor(v, 4);
            v += __shfl_xor(v, 8);
            if (r0 == 0) {
                int row = qb * 128 + wv * 32 + m * 16 + hi * 4 + q;
                atomicAdd(&Ssum[row], v);
            }
        }
    }
}

// ---- kernel 3: per-row term = log(S - PADROWS) - true_logit ----
// Kn element (r=lab&31, k=2*lane): addr = (lab>>5)*4096 + ((lab>>4)&1)*2048
//   + ((lane>>4)*16 + (lab&15))*32 + 2*(lane&15)
__global__ void term_kernel(const char* __restrict__ Qn,
                            const char* __restrict__ Kn,
                            const int* __restrict__ labels,
                            const float* __restrict__ Ssum,
                            float* __restrict__ T) {
    int w = (blockIdx.x * blockDim.x + threadIdx.x) >> 6;
    int lane = threadIdx.x & 63;
    if (w >= N_) return;
    int lab = labels[w];
    const unsigned char* qp = (const unsigned char*)(Qn + (size_t)w * 128 + 2 * lane);
    const unsigned char* kp = (const unsigned char*)(Kn
                      + ((size_t)(lab >> 5)) * 4096 + (((lab >> 4) & 1) << 11)
                      + (((lane >> 4) * 16 + (lab & 15)) << 5) + ((lane & 15) << 1));
    float d = from_fp8(qp[0]) * from_fp8(kp[0])
            + from_fp8(qp[1]) * from_fp8(kp[1]);
    #pragma unroll
    for (int off = 32; off; off >>= 1) d += __shfl_xor(d, off);
    if (lane == 0) T[w] = logf(Ssum[w] - PADROWS_) - d * LN2_;
}

// ---- kernel 4: mean over N ----
__global__ void reduce_kernel(const float* __restrict__ T, float* __restrict__ out) {
    __shared__ float sm[4];
    float s = 0.f;
    for (int i = threadIdx.x; i < N_; i += 256) s += T[i];
    #pragma unroll
    for (int off = 32; off; off >>= 1) s += __shfl_xor(s, off);
    if ((threadIdx.x & 63) == 0) sm[threadIdx.x >> 6] = s;
    __syncthreads();
    if (threadIdx.x == 0) out[0] = (sm[0] + sm[1] + sm[2] + sm[3]) * (1.0f / (float)N_);
}

extern "C" void kernel_launch(void* const* d_in, const int* in_sizes, int n_in,
                              void* d_out, int out_size, void* d_ws, size_t ws_size,
                              hipStream_t stream) {
    (void)in_sizes; (void)n_in; (void)out_size; (void)ws_size;
    const float* Q   = (const float*)d_in[0];
    const float* K   = (const float*)d_in[1];
    const int* loc   = (const int*)d_in[2];
    const int* labels= (const int*)d_in[3];
    float* out = (float*)d_out;

    char* ws = (char*)d_ws;
    char* Kn    = ws;                                   // 3136*4096 = 12,845,056 B
    char* Qn    = ws + 12845056;                        // N_*128    =     524,288 B
    float* Ssum = (float*)(ws + 12845056 + 524288);     // N_*4
    float* T    = Ssum + N_;                            // N_*4

    prep_kernel<<<VSTRIPS_ + N_ / 4, 256, 0, stream>>>(K, Q, loc, Kn, Qn, Ssum);
    ce_main<<<dim3(32, NPHASE_), 256, 0, stream>>>(Qn, Kn, Ssum);
    term_kernel<<<N_ / 4, 256, 0, stream>>>(Qn, Kn, labels, Ssum, T);
    reduce_kernel<<<1, 256, 0, stream>>>(T, out);
}